// Round 2
// baseline (5944.472 us; speedup 1.0000x reference)
//
#include <hip/hip_runtime.h>
#include <math.h>

// MetalWallQEQ: reciprocal-space Ewald QEQ for metal-wall charges.
//  out[i] = q[i] for electrolyte atoms; for metal atoms solve
//  [[A+J I, 1],[1^T,0]][q;lam]=[B;0],  A_ij=(4pi/V) sum_k kfac cos(k.(ri-rj)),
//  B = -field(metal) from electrolyte charges.
// Implementation: half-k symmetry (7812 pts, weight 2), on-the-fly sincos via
// fractional coords, triangular fp32 LDS-tiled A-build, 2-RHS Chronopoulos-Gear CG.

#define NA 4096
#define NM 2048
#define METAL_Z 79
#define KH 7812          // (25^3-1)/2 half k-points
#define KHP 7936         // padded to 62*128 (pad entries have w=0)
#define NIT 150          // fixed CG iterations (graph-friendly)
#define TWO_PI 6.283185307179586f

// ---- workspace byte offsets (total ~17.7 MB) ----
#define OFF_CONSTS 0        // [0..8]=invT(cell) row-major, [9]=pref=4pi/V, [10]=J
#define OFF_SUMS   256      // [2]=lambda
#define OFF_DOTS   512      // gamma1,gamma2,delta1,delta2 per iter (4*NIT floats)
#define OFF_KTAB   4096     // KHP * {gx,gy,gz,w} floats
#define OFF_FRAC   131072   // NA * {fx,fy,fz,0} fractional coords
#define OFF_MLIST  196608   // NM ints: metal position -> atom index
#define OFF_POSOF  204800   // NA ints: atom -> metal position (metal only)
#define OFF_SRW    221184   // KHP floats: w*Re S(k)
#define OFF_SIW    252928   // KHP floats: w*Im S(k)
#define OFF_BPART  284672   // 62*NM floats: field partials
#define OFF_B      792576   // NM floats
#define OFF_VEC    800768   // x1,x2,r1,r2,w1,w2,p1,p2,s1,s2 (each NM floats)
#define OFF_A      917504   // NM*NM floats (includes +J on diagonal)

__device__ __forceinline__ void sc_frac(float u, float& s, float& c) {
    // sin/cos of 2*pi*u, u reduced to [0,1) first for precision
    float t = u - floorf(u);
    __sincosf(TWO_PI * t, &s, &c);
}

// -------- setup: cell inverse, fractional coords, metal scan, zero dots --------
__global__ void k_setup(const float* __restrict__ pos, const float* __restrict__ cell,
                        const float* __restrict__ Jraw, const int* __restrict__ an,
                        float* __restrict__ wsf) {
    int tid = threadIdx.x;
    __shared__ float sM[9];
    __shared__ int sc[256];
    if (tid == 0) {
        float c00=cell[0],c01=cell[1],c02=cell[2];
        float c10=cell[3],c11=cell[4],c12=cell[5];
        float c20=cell[6],c21=cell[7],c22=cell[8];
        float det = c00*(c11*c22-c12*c21) - c01*(c10*c22-c12*c20) + c02*(c10*c21-c11*c20);
        float i00 =  (c11*c22 - c12*c21)/det;
        float i01 = -(c01*c22 - c02*c21)/det;
        float i02 =  (c01*c12 - c02*c11)/det;
        float i10 = -(c10*c22 - c12*c20)/det;
        float i11 =  (c00*c22 - c02*c20)/det;
        float i12 = -(c00*c12 - c02*c10)/det;
        float i20 =  (c10*c21 - c11*c20)/det;
        float i21 = -(c00*c21 - c01*c20)/det;
        float i22 =  (c00*c11 - c01*c10)/det;
        // invT[c][d] = inv[d][c]; frac_c = sum_d invT[c][d] * r_d
        sM[0]=i00; sM[1]=i10; sM[2]=i20;
        sM[3]=i01; sM[4]=i11; sM[5]=i21;
        sM[6]=i02; sM[7]=i12; sM[8]=i22;
        float vol = fabsf(det);
        for (int m=0;m<9;m++) wsf[OFF_CONSTS/4 + m] = sM[m];
        wsf[OFF_CONSTS/4 + 9]  = 12.566370614359172f / vol;   // 4pi/V
        wsf[OFF_CONSTS/4 + 10] = Jraw[0]*Jraw[0];
    }
    __syncthreads();
    float M0=sM[0],M1=sM[1],M2=sM[2],M3=sM[3],M4=sM[4],M5=sM[5],M6=sM[6],M7=sM[7],M8=sM[8];
    for (int i=tid; i<NA; i+=256) {
        float x=pos[3*i], y=pos[3*i+1], z=pos[3*i+2];
        wsf[OFF_FRAC/4 + 4*i+0] = M0*x + M1*y + M2*z;
        wsf[OFF_FRAC/4 + 4*i+1] = M3*x + M4*y + M5*z;
        wsf[OFF_FRAC/4 + 4*i+2] = M6*x + M7*y + M8*z;
        wsf[OFF_FRAC/4 + 4*i+3] = 0.f;
    }
    for (int i=tid; i<4*NIT+4; i+=256) wsf[OFF_DOTS/4 + i] = 0.f;
    if (tid < 4) wsf[OFF_SUMS/4 + tid] = 0.f;
    // metal prefix scan (deterministic ordering == np.where order)
    int cnt = 0;
    int base_i = tid*16;
    for (int j=0;j<16;j++) cnt += (an[base_i+j]==METAL_Z) ? 1 : 0;
    sc[tid] = cnt; __syncthreads();
    for (int off=1; off<256; off<<=1) {
        int v = (tid>=off) ? sc[tid-off] : 0;
        __syncthreads();
        sc[tid] += v;
        __syncthreads();
    }
    int base = sc[tid] - cnt;
    int* mlist = (int*)wsf + OFF_MLIST/4;
    int* posof = (int*)wsf + OFF_POSOF/4;
    for (int j=0;j<16;j++) {
        int i = base_i + j;
        if (an[i]==METAL_Z) { mlist[base] = i; posof[i] = base; base++; }
    }
}

// -------- k-table: integer triple + weight w = 2*pref*exp(-k2/2)/k2 --------
__global__ void k_ktab(float* __restrict__ wsf) {
    int k = blockIdx.x*256 + threadIdx.x;
    if (k >= KHP) return;
    float4 out;
    if (k < KH) {
        int gx = k/625 - 12;
        int rem = k%625;
        int gy = rem/25 - 12;
        int gz = rem%25 - 12;
        const float* M = wsf + OFF_CONSTS/4;
        float pref = M[9];
        float kx = TWO_PI*(gx*M[0] + gy*M[3] + gz*M[6]);
        float ky = TWO_PI*(gx*M[1] + gy*M[4] + gz*M[7]);
        float kz = TWO_PI*(gx*M[2] + gy*M[5] + gz*M[8]);
        float k2 = kx*kx + ky*ky + kz*kz;
        float kfac = __expf(-0.5f*k2) / k2;
        out = make_float4((float)gx, (float)gy, (float)gz, 2.f*pref*kfac);
    } else {
        out = make_float4(0.f, 0.f, 0.f, 0.f);
    }
    *(float4*)(wsf + OFF_KTAB/4 + 4*k) = out;
}

// -------- structure factors over electrolyte charges (metal q := 0) --------
__global__ void k_srsi(const float* __restrict__ q, const int* __restrict__ an,
                       float* __restrict__ wsf) {
    int k = blockIdx.x;
    int tid = threadIdx.x;
    float4 kt = *(const float4*)(wsf + OFF_KTAB/4 + 4*k);
    const float* frac = wsf + OFF_FRAC/4;
    float aR=0.f, aI=0.f;
    for (int i=tid; i<NA; i+=256) {
        float qa = (an[i]==METAL_Z) ? 0.f : q[i];
        float4 f = *(const float4*)(frac + 4*i);
        float u = kt.x*f.x + kt.y*f.y + kt.z*f.z;
        float s,c; sc_frac(u, s, c);
        aR += qa*c; aI += qa*s;
    }
    __shared__ float sR[256], sI[256];
    sR[tid]=aR; sI[tid]=aI; __syncthreads();
    for (int off=128; off>0; off>>=1) {
        if (tid<off) { sR[tid]+=sR[tid+off]; sI[tid]+=sI[tid+off]; }
        __syncthreads();
    }
    if (tid==0) {
        wsf[OFF_SRW/4 + k] = kt.w * sR[0];
        wsf[OFF_SIW/4 + k] = kt.w * sI[0];
    }
}

// -------- field at metal atoms (partial over k-chunks) --------
__global__ void k_field(float* __restrict__ wsf) {
    int kc = blockIdx.x;
    int m = blockIdx.y*256 + threadIdx.x;
    int atom = ((const int*)wsf)[OFF_MLIST/4 + m];
    float4 f = *(const float4*)(wsf + OFF_FRAC/4 + 4*atom);
    const float* kt = wsf + OFF_KTAB/4;
    const float* SrW = wsf + OFF_SRW/4;
    const float* SiW = wsf + OFF_SIW/4;
    float acc = 0.f;
    int k0 = kc*128;
    for (int j=0;j<128;j++) {
        int k = k0 + j;
        float4 g = *(const float4*)(kt + 4*k);
        float u = g.x*f.x + g.y*f.y + g.z*f.z;
        float s,c; sc_frac(u, s, c);
        acc = fmaf(c, SrW[k], fmaf(s, SiW[k], acc));
    }
    wsf[OFF_BPART/4 + kc*NM + m] = acc;
}

// -------- B = -field; init CG residuals r1=B, r2=1 --------
__global__ void k_bfinal(float* __restrict__ wsf) {
    int m = blockIdx.x*256 + threadIdx.x;
    float s = 0.f;
    for (int kc=0;kc<62;kc++) s += wsf[OFF_BPART/4 + kc*NM + m];
    float B = -s;
    wsf[OFF_B/4 + m] = B;
    float* vec = wsf + OFF_VEC/4;
    vec[4096 + m] = B;    // r1
    vec[6144 + m] = 1.f;  // r2
}

// -------- A build: triangular 64x64 tiles, on-the-fly sincos staging --------
__launch_bounds__(256)
__global__ void k_abuild(float* __restrict__ wsf) {
    __shared__ float cwi[32][64], swi[32][64], cjs[32][64], sjs[32][64];
    __shared__ float4 fi[64], fj[64];
    int tid = threadIdx.x;
    int bid = blockIdx.x;
    int bi = (int)((sqrtf(8.f*bid + 1.f) - 1.f)*0.5f);
    while ((bi+1)*(bi+2)/2 <= bid) bi++;
    while (bi*(bi+1)/2 > bid) bi--;
    int bj = bid - bi*(bi+1)/2;

    const int* mlist = (const int*)wsf + OFF_MLIST/4;
    const float* frac = wsf + OFF_FRAC/4;
    const float* ktab = wsf + OFF_KTAB/4;
    float J = wsf[OFF_CONSTS/4 + 10];

    if (tid < 64)        fi[tid]     = *(const float4*)(frac + 4*mlist[bi*64 + tid]);
    else if (tid < 128)  fj[tid-64]  = *(const float4*)(frac + 4*mlist[bj*64 + (tid-64)]);
    __syncthreads();

    int col = tid & 63;
    int kkb = tid >> 6;       // 0..3
    float4 fir = fi[col];
    float4 fjr = fj[col];
    int ty = tid >> 4, tx = tid & 15;
    int ty4 = ty*4, tx4 = tx*4;
    float acc[4][4] = {};

    for (int k0=0; k0<KHP; k0+=32) {
        #pragma unroll
        for (int it=0; it<8; it++) {
            int kk = kkb + it*4;
            float4 kt = *(const float4*)(ktab + 4*(k0+kk));
            float u = kt.x*fir.x + kt.y*fir.y + kt.z*fir.z;
            float s,c; sc_frac(u, s, c);
            cwi[kk][col] = kt.w*c; swi[kk][col] = kt.w*s;
            u = kt.x*fjr.x + kt.y*fjr.y + kt.z*fjr.z;
            sc_frac(u, s, c);
            cjs[kk][col] = c; sjs[kk][col] = s;
        }
        __syncthreads();
        #pragma unroll 4
        for (int kk=0; kk<32; kk++) {
            float4 ac  = *(const float4*)&cwi[kk][ty4];
            float4 as2 = *(const float4*)&swi[kk][ty4];
            float4 bc  = *(const float4*)&cjs[kk][tx4];
            float4 bs  = *(const float4*)&sjs[kk][tx4];
            float aC[4] = {ac.x, ac.y, ac.z, ac.w};
            float aS[4] = {as2.x, as2.y, as2.z, as2.w};
            float bC[4] = {bc.x, bc.y, bc.z, bc.w};
            float bS[4] = {bs.x, bs.y, bs.z, bs.w};
            #pragma unroll
            for (int a=0;a<4;a++)
                #pragma unroll
                for (int b=0;b<4;b++)
                    acc[a][b] = fmaf(aC[a], bC[b], fmaf(aS[a], bS[b], acc[a][b]));
        }
        __syncthreads();
    }

    float* A = wsf + OFF_A/4;
    int gi0 = bi*64 + ty4, gj0 = bj*64 + tx4;
    #pragma unroll
    for (int a=0;a<4;a++) {
        int gi = gi0 + a;
        #pragma unroll
        for (int b=0;b<4;b++) {
            int gj = gj0 + b;
            float v = acc[a][b] + ((gi==gj) ? J : 0.f);
            A[gi*NM + gj] = v;
            A[gj*NM + gi] = v;
        }
    }
}

// -------- CG matvec: w = A*r (2 RHS) + fused dots gamma=(r,r), delta=(r,w) --------
__global__ void k_mv(float* __restrict__ wsf, int iter) {
    const float* A = wsf + OFF_A/4;
    float* vec = wsf + OFF_VEC/4;
    const float* r1 = vec + 4096; const float* r2 = vec + 6144;
    float* w1 = vec + 8192; float* w2 = vec + 10240;
    int tid = threadIdx.x;
    int ri = tid >> 4, l = tid & 15;
    int row = blockIdx.x*16 + ri;
    const float* Arow = A + (size_t)row*NM;
    float acc1=0.f, acc2=0.f;
    #pragma unroll 4
    for (int c0=0; c0<NM; c0+=64) {
        float4 av  = *(const float4*)(Arow + c0 + l*4);
        float4 rv1 = *(const float4*)(r1 + c0 + l*4);
        float4 rv2 = *(const float4*)(r2 + c0 + l*4);
        acc1 += av.x*rv1.x + av.y*rv1.y + av.z*rv1.z + av.w*rv1.w;
        acc2 += av.x*rv2.x + av.y*rv2.y + av.z*rv2.z + av.w*rv2.w;
    }
    #pragma unroll
    for (int off=1; off<16; off<<=1) {
        acc1 += __shfl_xor(acc1, off);
        acc2 += __shfl_xor(acc2, off);
    }
    __shared__ float sd[4];
    if (tid==0) { sd[0]=0.f; sd[1]=0.f; sd[2]=0.f; sd[3]=0.f; }
    __syncthreads();
    if (l==0) {
        w1[row] = acc1; w2[row] = acc2;
        float rv1 = r1[row], rv2 = r2[row];
        atomicAdd(&sd[0], rv1*rv1);
        atomicAdd(&sd[1], rv2*rv2);
        atomicAdd(&sd[2], rv1*acc1);
        atomicAdd(&sd[3], rv2*acc2);
    }
    __syncthreads();
    if (tid<4) atomicAdd(wsf + OFF_DOTS/4 + iter*4 + tid, sd[tid]);
}

// -------- CG update (Chronopoulos-Gear; alpha/beta chain from dot history) --------
__global__ void k_up(float* __restrict__ wsf, int iter) {
    int i = blockIdx.x*256 + threadIdx.x;
    const float* dots = wsf + OFF_DOTS/4;
    float b1=0.f,a1=0.f,b2=0.f,a2=0.f,gp1=0.f,ap1=1.f,gp2=0.f,ap2=1.f;
    for (int j=0;j<=iter;j++) {
        float g1=dots[4*j+0], g2=dots[4*j+1], d1=dots[4*j+2], d2=dots[4*j+3];
        if (j==0) { b1=0.f; a1=g1/d1; b2=0.f; a2=g2/d2; }
        else {
            b1 = g1/gp1; a1 = g1/(d1 - b1*g1/ap1);
            b2 = g2/gp2; a2 = g2/(d2 - b2*g2/ap2);
        }
        gp1=g1; ap1=a1; gp2=g2; ap2=a2;
    }
    float* vec = wsf + OFF_VEC/4;
    float* x1=vec;        float* x2=vec+2048;
    float* r1=vec+4096;   float* r2=vec+6144;
    float* w1=vec+8192;   float* w2=vec+10240;
    float* p1=vec+12288;  float* p2=vec+14336;
    float* s1=vec+16384;  float* s2=vec+18432;

    float r1v=r1[i], w1v=w1[i];
    float p1v = (iter==0) ? r1v : fmaf(b1, p1[i], r1v);
    float s1v = (iter==0) ? w1v : fmaf(b1, s1[i], w1v);
    p1[i]=p1v; s1[i]=s1v;
    x1[i] = (iter==0) ? a1*p1v : fmaf(a1, p1v, x1[i]);
    r1[i] = fmaf(-a1, s1v, r1v);

    float r2v=r2[i], w2v=w2[i];
    float p2v = (iter==0) ? r2v : fmaf(b2, p2[i], r2v);
    float s2v = (iter==0) ? w2v : fmaf(b2, s2[i], w2v);
    p2[i]=p2v; s2[i]=s2v;
    x2[i] = (iter==0) ? a2*p2v : fmaf(a2, p2v, x2[i]);
    r2[i] = fmaf(-a2, s2v, r2v);
}

// -------- lambda = sum(x1)/sum(x2) --------
__global__ void k_sum(float* __restrict__ wsf) {
    int tid = threadIdx.x;
    float* vec = wsf + OFF_VEC/4;
    float s1=0.f, s2=0.f;
    for (int i=tid; i<NM; i+=256) { s1 += vec[i]; s2 += vec[2048+i]; }
    __shared__ float a[256], b[256];
    a[tid]=s1; b[tid]=s2; __syncthreads();
    for (int off=128; off>0; off>>=1) {
        if (tid<off) { a[tid]+=a[tid+off]; b[tid]+=b[tid+off]; }
        __syncthreads();
    }
    if (tid==0) wsf[OFF_SUMS/4 + 2] = a[0]/b[0];
}

// -------- assemble output --------
__global__ void k_out(const float* __restrict__ q, const int* __restrict__ an,
                      const float* __restrict__ wsf, float* __restrict__ out) {
    int i = blockIdx.x*256 + threadIdx.x;
    if (i >= NA) return;
    if (an[i]==METAL_Z) {
        int p = ((const int*)wsf)[OFF_POSOF/4 + i];
        float lam = wsf[OFF_SUMS/4 + 2];
        const float* vec = wsf + OFF_VEC/4;
        out[i] = vec[p] - lam*vec[2048 + p];
    } else {
        out[i] = q[i];
    }
}

extern "C" void kernel_launch(void* const* d_in, const int* in_sizes, int n_in,
                              void* d_out, int out_size, void* d_ws, size_t ws_size,
                              hipStream_t stream) {
    (void)in_sizes; (void)n_in; (void)out_size; (void)ws_size;
    const float* pos  = (const float*)d_in[0];
    const float* cell = (const float*)d_in[1];
    const float* q    = (const float*)d_in[2];
    const float* Jraw = (const float*)d_in[3];
    const int*   an   = (const int*)d_in[4];
    float* wsf = (float*)d_ws;
    float* out = (float*)d_out;

    k_setup<<<1, 256, 0, stream>>>(pos, cell, Jraw, an, wsf);
    k_ktab<<<KHP/256, 256, 0, stream>>>(wsf);
    k_srsi<<<KHP, 256, 0, stream>>>(q, an, wsf);
    k_field<<<dim3(62, 8), 256, 0, stream>>>(wsf);
    k_bfinal<<<NM/256, 256, 0, stream>>>(wsf);
    k_abuild<<<528, 256, 0, stream>>>(wsf);
    for (int it=0; it<NIT; ++it) {
        k_mv<<<128, 256, 0, stream>>>(wsf, it);
        k_up<<<NM/256, 256, 0, stream>>>(wsf, it);
    }
    k_sum<<<1, 256, 0, stream>>>(wsf);
    k_out<<<NA/256, 256, 0, stream>>>(q, an, wsf, out);
}